// Round 3
// baseline (506.816 us; speedup 1.0000x reference)
//
#include <hip/hip_runtime.h>
#include <stdint.h>
#include <math.h>

typedef unsigned short u16;
typedef __attribute__((ext_vector_type(8))) short short8;
typedef __attribute__((ext_vector_type(8))) _Float16 half8;
typedef __attribute__((ext_vector_type(4))) float float4v;
typedef __attribute__((ext_vector_type(16))) float float16v;
typedef __attribute__((ext_vector_type(4))) u16 ushort4v;

#define T_SEQ 2048
#define NB 2
#define NE 2048
#define NH 16
#define NKV 4
#define HD 128
#define KDIM 2048

union Frag { short8 s; half8 h; };

__device__ inline u16 f32_bf16(float f) {
    union { float f; uint32_t u; } v; v.f = f;
    uint32_t u = v.u;
    return (u16)((u + 0x7fffu + ((u >> 16) & 1u)) >> 16);
}
__device__ inline u16 f32_f16(float f) {
    union { _Float16 h; u16 u; } v; v.h = (_Float16)f;
    return v.u;
}

__device__ inline void gload16(const u16* g, u16* l) {
    __builtin_amdgcn_global_load_lds(
        (const __attribute__((address_space(1))) void*)g,
        (__attribute__((address_space(3))) void*)l, 16, 0, 0);
}

// ---------------- conversion kernels ----------------
__global__ void conv_f16(const float* __restrict__ in, u16* __restrict__ out) {
    int i = blockIdx.x * blockDim.x + threadIdx.x;
    float4 v = ((const float4*)in)[i];
    ushort4v o;
    o.x = f32_f16(v.x); o.y = f32_f16(v.y); o.z = f32_f16(v.z); o.w = f32_f16(v.w);
    *(ushort4v*)(out + (size_t)i * 4) = o;
}

template<bool TO_F16>
__global__ void transpose_convert(const float* __restrict__ in, u16* __restrict__ out,
                                  int K, int N) {
    __shared__ float tile[32][33];
    int n0 = blockIdx.x * 32, k0 = blockIdx.y * 32;
    int tx = threadIdx.x, ty = threadIdx.y;   // 32 x 8
    for (int i = 0; i < 32; i += 8)
        tile[ty + i][tx] = in[(size_t)(k0 + ty + i) * N + n0 + tx];
    __syncthreads();
    for (int i = 0; i < 32; i += 8) {
        float v = tile[tx][ty + i];
        out[(size_t)(n0 + ty + i) * K + k0 + tx] = TO_F16 ? f32_f16(v) : f32_bf16(v);
    }
}

__global__ void rope_tab(float* __restrict__ ctab, float* __restrict__ stab) {
    int i = blockIdx.x * blockDim.x + threadIdx.x;   // < 2048*64
    int t = i >> 6, j = i & 63;
    float freqf = (float)pow(10000.0, -(double)j / 1024.0);
    float angf = (float)t * freqf;          // fp32 rounding like np.outer
    double a = (double)angf;
    ctab[i] = (float)cos(a);
    stab[i] = (float)sin(a);
}

// ---------------- GEMM (m97 structure): C[M,N] = A[M,K] @ Bt[N,K]^T ----------------
// MODE: 0 = Q (rope->bf16, [B,H,T,D]), 3 = OUT (fp32 + bias -> d_out),
//       4 = fused KV (col<512: K rope->[B,KVH,T,D]; col>=512: V ->[B,KVH,D,T])
template<int MODE, bool F16IN>
__global__ __launch_bounds__(256)
void gemm_bt(const u16* __restrict__ A, const u16* __restrict__ Bt,
             const float* __restrict__ bias, const float* __restrict__ bias2,
             u16* __restrict__ outU, u16* __restrict__ outU2, float* __restrict__ outF,
             const float* __restrict__ ctab, const float* __restrict__ stab) {
    __shared__ u16 Alds[128 * 32];
    __shared__ u16 Blds[128 * 32];
    int tid = threadIdx.x;
    int wid = tid >> 6, lane = tid & 63;
    int quad = lane >> 4, l16 = lane & 15;
    int wr = wid >> 1, wc = wid & 1;
    int m0 = blockIdx.x * 128, n0 = blockIdx.y * 128;

    float4v acc[4][4];
    for (int i = 0; i < 4; i++) for (int j = 0; j < 4; j++) acc[i][j] = (float4v){0,0,0,0};

    int srow = tid >> 2;            // 0..63
    int scol = (tid & 3) * 8;       // u16 within 32-wide k-slab
    const u16* Ag0 = A + (size_t)(m0 + srow) * KDIM + scol;
    const u16* Ag1 = Ag0 + (size_t)64 * KDIM;
    const u16* Bg0 = Bt + (size_t)(n0 + srow) * KDIM + scol;
    const u16* Bg1 = Bg0 + (size_t)64 * KDIM;
    u16* Al = Alds + tid * 8;       // dest = wave-uniform base + lane*16B
    u16* Bl = Blds + tid * 8;

    for (int k0 = 0; k0 < KDIM; k0 += 32) {
        __syncthreads();
        gload16(Ag0 + k0, Al);
        gload16(Ag1 + k0, Al + 2048);
        gload16(Bg0 + k0, Bl);
        gload16(Bg1 + k0, Bl + 2048);
        __syncthreads();

        Frag af[4], bf[4];
#pragma unroll
        for (int i = 0; i < 4; i++)
            af[i].s = *(const short8*)&Alds[(wr * 64 + i * 16 + l16) * 32 + quad * 8];
#pragma unroll
        for (int j = 0; j < 4; j++)
            bf[j].s = *(const short8*)&Blds[(wc * 64 + j * 16 + l16) * 32 + quad * 8];
#pragma unroll
        for (int i = 0; i < 4; i++)
#pragma unroll
            for (int j = 0; j < 4; j++) {
                if (F16IN)
                    acc[i][j] = __builtin_amdgcn_mfma_f32_16x16x32_f16(af[i].h, bf[j].h, acc[i][j], 0, 0, 0);
                else
                    acc[i][j] = __builtin_amdgcn_mfma_f32_16x16x32_bf16(af[i].s, bf[j].s, acc[i][j], 0, 0, 0);
            }
    }

    // epilogue
    for (int i = 0; i < 4; i++) {
        int mbase = m0 + wr * 64 + i * 16 + quad * 4;
        for (int j = 0; j < 4; j++) {
            int col = n0 + wc * 64 + j * 16 + l16;
            float bcol = (MODE == 4 && col >= 512) ? bias2[col - 512] : bias[col];
            for (int r = 0; r < 4; r++) {
                int m = mbase + r;
                float val = acc[i][j][r] + bcol;
                if (MODE == 3) {
                    outF[(size_t)m * NE + col] = val;
                } else if (MODE == 4 && col >= 512) {   // V
                    int b = m >> 11, t = m & 2047;
                    int c2 = col - 512;
                    int h = c2 >> 7, d = c2 & 127;
                    outU2[(((size_t)(b * NKV + h)) * HD + d) * T_SEQ + t] = f32_bf16(val);
                } else {                                 // Q or K rope
                    int b = m >> 11, t = m & 2047;
                    int h = col >> 7, d = col & 127;
                    int jj = d >> 1;
                    float c = ctab[t * 64 + jj];
                    float s = stab[t * 64 + jj];
                    float partner = __shfl_xor(val, 1, 64);
                    float o = (d & 1) ? (partner * s + val * c) : (val * c - partner * s);
                    u16 ob = f32_bf16(o);
                    if (MODE == 0)
                        outU[(((size_t)(b * NH + h)) * T_SEQ + t) * HD + d] = ob;
                    else
                        outU[(((size_t)(b * NKV + h)) * T_SEQ + t) * HD + d] = ob;
                }
            }
        }
    }
}

// ---------------- flash attention v3 (transposed-S AND transposed-O) ----------------
// Grid 512 blocks; remap gives CU-balanced qt pairing. O accumulated as O^T so
// online-softmax alpha / l are per-lane scalars (no cross-lane ops in the loop).
__global__ __launch_bounds__(256, 3)
void attn_kernel(const u16* __restrict__ Qr, const u16* __restrict__ Kr,
                 const u16* __restrict__ Vt, u16* __restrict__ Oout) {
    __shared__ u16 smem[27136];            // 54272 B total
    u16* klds = smem;                      // K tile [s=64][d=128] stride 136
    u16* vlds = smem + 8704;               // V^T tile [d=128][s=64] stride 72
    u16* plds = smem + 17920;              // per-wave P [t=32][s=64] stride 72
    int tid = threadIdx.x;
    int wid = tid >> 6, lane = tid & 63;
    int l32 = lane & 31, hh = lane >> 5;

    int lin = blockIdx.x + (blockIdx.y << 4);
    int g = lin >> 5, bh = lin & 31;
    int qt = (lin < 256) ? (15 - g) : (g - 8);   // balance: CU gets qt and 15-qt
    int b = bh >> 4, hd = bh & 15, kvh = hd >> 2;
    int t0 = qt * 128;

    const u16* Qb = Qr + (((size_t)(b * NH + hd)) * T_SEQ + t0 + wid * 32) * HD;
    const u16* Kb = Kr + ((size_t)(b * NKV + kvh)) * T_SEQ * HD;
    const u16* Vb = Vt + ((size_t)(b * NKV + kvh)) * HD * T_SEQ;

    // Q as B-operand frags: col = t = l32, k = d
    short8 qf[8];
#pragma unroll
    for (int ks = 0; ks < 8; ks++)
        qf[ks] = *(const short8*)(Qb + (size_t)l32 * HD + ks * 16 + hh * 8);

    float16v oacc[4];   // O^T: rows d (dt*32 block), cols t (= l32)
#pragma unroll
    for (int dt = 0; dt < 4; dt++)
        oacc[dt] = (float16v){0,0,0,0,0,0,0,0,0,0,0,0,0,0,0,0};
    float m_run = -INFINITY, l_run = 0.f;

    int ksr = tid >> 2, kc = (tid & 3) * 32;   // K staging: row s, col base (u16)
    int vdr = tid >> 1, vc = (tid & 1) * 32;   // V staging: row d, col base (u16)
    u16* pw = plds + wid * 32 * 72;

    int nst = 2 * qt + 2;

    {   // prologue: stage tile 0
        const u16* ksrc = Kb + (size_t)ksr * HD + kc;
        const u16* vsrc = Vb + (size_t)vdr * T_SEQ + vc;
        short8 kr0[4], vr0[4];
#pragma unroll
        for (int i = 0; i < 4; i++) kr0[i] = *(const short8*)(ksrc + i * 8);
#pragma unroll
        for (int i = 0; i < 4; i++) vr0[i] = *(const short8*)(vsrc + i * 8);
#pragma unroll
        for (int i = 0; i < 4; i++) *(short8*)&klds[ksr * 136 + kc + i * 8] = kr0[i];
#pragma unroll
        for (int i = 0; i < 4; i++) *(short8*)&vlds[vdr * 72 + vc + i * 8] = vr0[i];
    }
    __syncthreads();

    for (int st = 0; st < nst; st++) {
        short8 krg[4], vrg[4];
        bool more = (st + 1 < nst);
        if (more) {   // prefetch next K/V tile into registers
            const u16* ksrc = Kb + ((size_t)(st + 1) * 64 + ksr) * HD + kc;
            const u16* vsrc = Vb + (size_t)vdr * T_SEQ + (st + 1) * 64 + vc;
#pragma unroll
            for (int i = 0; i < 4; i++) krg[i] = *(const short8*)(ksrc + i * 8);
#pragma unroll
            for (int i = 0; i < 4; i++) vrg[i] = *(const short8*)(vsrc + i * 8);
        }

        // S^T = K * Q^T : rows = s (2 tiles of 32), cols = t (32)
        float16v sfa[2];
        sfa[0] = (float16v){0,0,0,0,0,0,0,0,0,0,0,0,0,0,0,0};
        sfa[1] = (float16v){0,0,0,0,0,0,0,0,0,0,0,0,0,0,0,0};
#pragma unroll
        for (int ks = 0; ks < 8; ks++) {
            short8 kf0 = *(const short8*)&klds[l32 * 136 + ks * 16 + hh * 8];
            short8 kf1 = *(const short8*)&klds[(32 + l32) * 136 + ks * 16 + hh * 8];
            sfa[0] = __builtin_amdgcn_mfma_f32_32x32x16_bf16(kf0, qf[ks], sfa[0], 0, 0, 0);
            sfa[1] = __builtin_amdgcn_mfma_f32_32x32x16_bf16(kf1, qf[ks], sfa[1], 0, 0, 0);
        }

        int tg = t0 + wid * 32 + l32;
        if (st >= 2 * qt) {   // causal mask on diagonal tiles
#pragma unroll
            for (int stile = 0; stile < 2; stile++)
#pragma unroll
                for (int r = 0; r < 16; r++) {
                    int s = st * 64 + stile * 32 + (r & 3) + 8 * (r >> 2) + 4 * hh;
                    if (s > tg) sfa[stile][r] = -INFINITY;
                }
        }

        // online softmax over s (in-lane 32 values + one cross-half shfl)
        float mx = -INFINITY;
#pragma unroll
        for (int stile = 0; stile < 2; stile++)
#pragma unroll
            for (int r = 0; r < 16; r++) mx = fmaxf(mx, sfa[stile][r]);
        mx = fmaxf(mx, __shfl_xor(mx, 32, 64));
        float mnew = fmaxf(m_run, mx);
        float alpha = __expf(m_run - mnew);
        float psum = 0.f;
#pragma unroll
        for (int stile = 0; stile < 2; stile++)
#pragma unroll
            for (int r = 0; r < 16; r++) {
                float p = __expf(sfa[stile][r] - mnew);
                sfa[stile][r] = p;
                psum += p;
            }
        psum += __shfl_xor(psum, 32, 64);
        l_run = l_run * alpha + psum;
        m_run = mnew;

        // write P^T -> plds[t][s] packed b64 (per-wave region, no barrier needed)
#pragma unroll
        for (int stile = 0; stile < 2; stile++)
#pragma unroll
            for (int gq = 0; gq < 4; gq++) {
                ushort4v pk;
                pk.x = f32_bf16(sfa[stile][gq * 4 + 0]);
                pk.y = f32_bf16(sfa[stile][gq * 4 + 1]);
                pk.z = f32_bf16(sfa[stile][gq * 4 + 2]);
                pk.w = f32_bf16(sfa[stile][gq * 4 + 3]);
                *(ushort4v*)&pw[l32 * 72 + stile * 32 + gq * 8 + hh * 4] = pk;
            }

        // rescale O^T by alpha — per-lane scalar now
#pragma unroll
        for (int dt = 0; dt < 4; dt++)
#pragma unroll
            for (int r = 0; r < 16; r++) oacc[dt][r] *= alpha;

        // O^T += V^T * P^T : A = V^T [d][s-k], B = P^T (lane n = t, k = s)
#pragma unroll
        for (int ks2 = 0; ks2 < 4; ks2++) {
            short8 pf = *(const short8*)&pw[l32 * 72 + ks2 * 16 + hh * 8];
#pragma unroll
            for (int dt = 0; dt < 4; dt++) {
                short8 vf = *(const short8*)&vlds[(dt * 32 + l32) * 72 + ks2 * 16 + hh * 8];
                oacc[dt] = __builtin_amdgcn_mfma_f32_32x32x16_bf16(vf, pf, oacc[dt], 0, 0, 0);
            }
        }

        if (more) {
            __syncthreads();   // everyone done reading current K/V
#pragma unroll
            for (int i = 0; i < 4; i++) *(short8*)&klds[ksr * 136 + kc + i * 8] = krg[i];
#pragma unroll
            for (int i = 0; i < 4; i++) *(short8*)&vlds[vdr * 72 + vc + i * 8] = vrg[i];
            __syncthreads();
        }
    }

    // epilogue: scale (per-lane), transpose O^T -> O via per-wave LDS scratch
    const float scale = 0.022097086912079608f;   // 2048^-0.5
    float sc = scale / l_run;
    __syncthreads();                       // done with vlds/klds
    u16* ow = smem + wid * 4352;           // [t=32][d=128] stride 136
#pragma unroll
    for (int dt = 0; dt < 4; dt++)
#pragma unroll
        for (int gq = 0; gq < 4; gq++) {
            ushort4v pk;
            pk.x = f32_bf16(oacc[dt][gq * 4 + 0] * sc);
            pk.y = f32_bf16(oacc[dt][gq * 4 + 1] * sc);
            pk.z = f32_bf16(oacc[dt][gq * 4 + 2] * sc);
            pk.w = f32_bf16(oacc[dt][gq * 4 + 3] * sc);
            *(ushort4v*)&ow[l32 * 136 + dt * 32 + gq * 8 + hh * 4] = pk;
        }
    // same-wave read-back (compiler inserts lgkmcnt wait), coalesced store
    int tl = lane >> 4, dcol = (lane & 15) * 8;
#pragma unroll
    for (int ch = 0; ch < 8; ch++) {
        int t_local = tl + ch * 4;
        short8 ov = *(const short8*)&ow[t_local * 136 + dcol];
        *(short8*)&Oout[((size_t)(b * T_SEQ) + t0 + wid * 32 + t_local) * NE + hd * HD + dcol] = ov;
    }
}

// ---------------- launch ----------------
extern "C" void kernel_launch(void* const* d_in, const int* in_sizes, int n_in,
                              void* d_out, int out_size, void* d_ws, size_t ws_size,
                              hipStream_t stream) {
    const float* x  = (const float*)d_in[0];
    const float* Wq = (const float*)d_in[1];
    const float* bq = (const float*)d_in[2];
    const float* Wk = (const float*)d_in[3];
    const float* bk = (const float*)d_in[4];
    const float* Wv = (const float*)d_in[5];
    const float* bv = (const float*)d_in[6];
    const float* Wo = (const float*)d_in[7];
    const float* bo = (const float*)d_in[8];
    float* out = (float*)d_out;
    char* ws = (char*)d_ws;

    // aliasing: ao reuses xh (xh dead after KV gemm); wot reuses wqt (dead after Q gemm)
    u16* xh   = (u16*)(ws);                      // 16 MB   [also ao]
    u16* wqt  = (u16*)(ws + 16777216);           // 8 MB    [also wot]
    u16* wkt  = (u16*)(ws + 25165824);           // 2 MB  } contiguous [n=1024][k=2048]
    u16* wvt  = (u16*)(ws + 27262976);           // 2 MB  }
    u16* qr   = (u16*)(ws + 29360128);           // 16 MB
    u16* kr   = (u16*)(ws + 46137344);           // 4 MB
    u16* vt   = (u16*)(ws + 50331648);           // 4 MB
    float* ctab = (float*)(ws + 54525952);       // 0.5 MB
    float* stab = (float*)(ws + 55050240);       // 0.5 MB
    u16* ao  = xh;
    u16* wot = wqt;

    conv_f16<<<8192, 256, 0, stream>>>(x, xh);
    transpose_convert<true><<<dim3(64, 64), dim3(32, 8), 0, stream>>>(Wq, wqt, 2048, 2048);
    transpose_convert<true><<<dim3(16, 64), dim3(32, 8), 0, stream>>>(Wk, wkt, 2048, 512);
    transpose_convert<true><<<dim3(16, 64), dim3(32, 8), 0, stream>>>(Wv, wvt, 2048, 512);
    rope_tab<<<512, 256, 0, stream>>>(ctab, stab);

    gemm_bt<0, true><<<dim3(32, 16), 256, 0, stream>>>(xh, wqt, bq, nullptr, qr, nullptr, nullptr, ctab, stab);
    gemm_bt<4, true><<<dim3(32, 8), 256, 0, stream>>>(xh, wkt, bk, bv, kr, vt, nullptr, ctab, stab);

    // Wo transpose after Q gemm (wqt dead), before final gemm
    transpose_convert<false><<<dim3(64, 64), dim3(32, 8), 0, stream>>>(Wo, wot, 2048, 2048);

    attn_kernel<<<dim3(16, 32), 256, 0, stream>>>(qr, kr, vt, ao);

    gemm_bt<3, false><<<dim3(32, 16), 256, 0, stream>>>(ao, wot, bo, nullptr, nullptr, nullptr, out, ctab, stab);
}

// Round 4
// 499.867 us; speedup vs baseline: 1.0139x; 1.0139x over previous
//
#include <hip/hip_runtime.h>
#include <stdint.h>
#include <math.h>

typedef unsigned short u16;
typedef __attribute__((ext_vector_type(8))) short short8;
typedef __attribute__((ext_vector_type(8))) _Float16 half8;
typedef __attribute__((ext_vector_type(4))) float float4v;
typedef __attribute__((ext_vector_type(16))) float float16v;
typedef __attribute__((ext_vector_type(4))) u16 ushort4v;

#define T_SEQ 2048
#define NB 2
#define NE 2048
#define NH 16
#define NKV 4
#define HD 128
#define KDIM 2048

union Frag { short8 s; half8 h; };

__device__ inline u16 f32_bf16(float f) {
    union { float f; uint32_t u; } v; v.f = f;
    uint32_t u = v.u;
    return (u16)((u + 0x7fffu + ((u >> 16) & 1u)) >> 16);
}
__device__ inline u16 f32_f16(float f) {
    union { _Float16 h; u16 u; } v; v.h = (_Float16)f;
    return v.u;
}

// ---------------- conversion kernels ----------------
__global__ void conv_f16(const float* __restrict__ in, u16* __restrict__ out) {
    int i = blockIdx.x * blockDim.x + threadIdx.x;
    float4 v = ((const float4*)in)[i];
    ushort4v o;
    o.x = f32_f16(v.x); o.y = f32_f16(v.y); o.z = f32_f16(v.z); o.w = f32_f16(v.w);
    *(ushort4v*)(out + (size_t)i * 4) = o;
}

template<bool TO_F16>
__global__ void transpose_convert(const float* __restrict__ in, u16* __restrict__ out,
                                  int K, int N) {
    __shared__ float tile[32][33];
    int n0 = blockIdx.x * 32, k0 = blockIdx.y * 32;
    int tx = threadIdx.x, ty = threadIdx.y;   // 32 x 8
    for (int i = 0; i < 32; i += 8)
        tile[ty + i][tx] = in[(size_t)(k0 + ty + i) * N + n0 + tx];
    __syncthreads();
    for (int i = 0; i < 32; i += 8) {
        float v = tile[tx][ty + i];
        out[(size_t)(n0 + ty + i) * K + k0 + tx] = TO_F16 ? f32_f16(v) : f32_bf16(v);
    }
}

__global__ void rope_tab(float* __restrict__ ctab, float* __restrict__ stab) {
    int i = blockIdx.x * blockDim.x + threadIdx.x;   // < 2048*64
    int t = i >> 6, j = i & 63;
    float freqf = (float)pow(10000.0, -(double)j / 1024.0);
    float angf = (float)t * freqf;          // fp32 rounding like np.outer
    double a = (double)angf;
    ctab[i] = (float)cos(a);
    stab[i] = (float)sin(a);
}

// ---------------- GEMM: C[M,N] = A[M,K] @ Bt[N,K]^T, reg-staged + prefetch ----------------
// MODE: 0 = Q (rope->bf16, [B,H,T,D]), 3 = OUT (fp32 + bias -> d_out),
//       4 = fused KV (col<512: K rope->[B,KVH,T,D]; col>=512: V ->[B,KVH,D,T])
template<int MODE, bool F16IN>
__global__ __launch_bounds__(256)
void gemm_bt(const u16* __restrict__ A, const u16* __restrict__ Bt,
             const float* __restrict__ bias, const float* __restrict__ bias2,
             u16* __restrict__ outU, u16* __restrict__ outU2, float* __restrict__ outF,
             const float* __restrict__ ctab, const float* __restrict__ stab) {
    __shared__ u16 Alds[128 * 40];
    __shared__ u16 Blds[128 * 40];
    int tid = threadIdx.x;
    int wid = tid >> 6, lane = tid & 63;
    int quad = lane >> 4, l16 = lane & 15;
    int wr = wid >> 1, wc = wid & 1;
    int m0 = blockIdx.x * 128, n0 = blockIdx.y * 128;

    float4v acc[4][4];
    for (int i = 0; i < 4; i++) for (int j = 0; j < 4; j++) acc[i][j] = (float4v){0,0,0,0};

    int sr = tid >> 2;      // 0..63
    int sq = tid & 3;       // k-group of 8
    const u16* Ag = A + (size_t)(m0 + sr) * KDIM + sq * 8;
    const u16* Bg = Bt + (size_t)(n0 + sr) * KDIM + sq * 8;

    // prologue: load k-slab 0 into registers
    short8 av0 = *(const short8*)(Ag);
    short8 av1 = *(const short8*)(Ag + (size_t)64 * KDIM);
    short8 bv0 = *(const short8*)(Bg);
    short8 bv1 = *(const short8*)(Bg + (size_t)64 * KDIM);

    for (int k0 = 0; k0 < KDIM; k0 += 32) {
        // prefetch next slab BEFORE the barrier: its vmcnt wait is deferred
        // to next iteration's ds_write, hidden under this iteration's MFMAs
        short8 nav0 = av0, nav1 = av1, nbv0 = bv0, nbv1 = bv1;
        if (k0 + 32 < KDIM) {
            nav0 = *(const short8*)(Ag + k0 + 32);
            nav1 = *(const short8*)(Ag + (size_t)64 * KDIM + k0 + 32);
            nbv0 = *(const short8*)(Bg + k0 + 32);
            nbv1 = *(const short8*)(Bg + (size_t)64 * KDIM + k0 + 32);
        }
        __syncthreads();
        *(short8*)&Alds[sr * 40 + sq * 8] = av0;
        *(short8*)&Alds[(sr + 64) * 40 + sq * 8] = av1;
        *(short8*)&Blds[sr * 40 + sq * 8] = bv0;
        *(short8*)&Blds[(sr + 64) * 40 + sq * 8] = bv1;
        __syncthreads();

        Frag af[4], bf[4];
#pragma unroll
        for (int i = 0; i < 4; i++)
            af[i].s = *(const short8*)&Alds[(wr * 64 + i * 16 + l16) * 40 + quad * 8];
#pragma unroll
        for (int j = 0; j < 4; j++)
            bf[j].s = *(const short8*)&Blds[(wc * 64 + j * 16 + l16) * 40 + quad * 8];
#pragma unroll
        for (int i = 0; i < 4; i++)
#pragma unroll
            for (int j = 0; j < 4; j++) {
                if (F16IN)
                    acc[i][j] = __builtin_amdgcn_mfma_f32_16x16x32_f16(af[i].h, bf[j].h, acc[i][j], 0, 0, 0);
                else
                    acc[i][j] = __builtin_amdgcn_mfma_f32_16x16x32_bf16(af[i].s, bf[j].s, acc[i][j], 0, 0, 0);
            }
        av0 = nav0; av1 = nav1; bv0 = nbv0; bv1 = nbv1;
    }

    // epilogue
    for (int i = 0; i < 4; i++) {
        int mbase = m0 + wr * 64 + i * 16 + quad * 4;
        for (int j = 0; j < 4; j++) {
            int col = n0 + wc * 64 + j * 16 + l16;
            float bcol = (MODE == 4 && col >= 512) ? bias2[col - 512] : bias[col];
            for (int r = 0; r < 4; r++) {
                int m = mbase + r;
                float val = acc[i][j][r] + bcol;
                if (MODE == 3) {
                    outF[(size_t)m * NE + col] = val;
                } else if (MODE == 4 && col >= 512) {   // V
                    int b = m >> 11, t = m & 2047;
                    int c2 = col - 512;
                    int h = c2 >> 7, d = c2 & 127;
                    outU2[(((size_t)(b * NKV + h)) * HD + d) * T_SEQ + t] = f32_bf16(val);
                } else {                                 // Q or K rope
                    int b = m >> 11, t = m & 2047;
                    int h = col >> 7, d = col & 127;
                    int jj = d >> 1;
                    float c = ctab[t * 64 + jj];
                    float s = stab[t * 64 + jj];
                    float partner = __shfl_xor(val, 1, 64);
                    float o = (d & 1) ? (partner * s + val * c) : (val * c - partner * s);
                    u16 ob = f32_bf16(o);
                    if (MODE == 0)
                        outU[(((size_t)(b * NH + h)) * T_SEQ + t) * HD + d] = ob;
                    else
                        outU[(((size_t)(b * NKV + h)) * T_SEQ + t) * HD + d] = ob;
                }
            }
        }
    }
}

// ---------------- flash attention v3 (transposed-S AND transposed-O) ----------------
// Grid 512 blocks; remap gives CU-balanced qt pairing. O accumulated as O^T so
// online-softmax alpha / l are per-lane scalars (no cross-lane ops in the loop).
__global__ __launch_bounds__(256, 3)
void attn_kernel(const u16* __restrict__ Qr, const u16* __restrict__ Kr,
                 const u16* __restrict__ Vt, u16* __restrict__ Oout) {
    __shared__ u16 smem[27136];            // 54272 B total
    u16* klds = smem;                      // K tile [s=64][d=128] stride 136
    u16* vlds = smem + 8704;               // V^T tile [d=128][s=64] stride 72
    u16* plds = smem + 17920;              // per-wave P [t=32][s=64] stride 72
    int tid = threadIdx.x;
    int wid = tid >> 6, lane = tid & 63;
    int l32 = lane & 31, hh = lane >> 5;

    int lin = blockIdx.x + (blockIdx.y << 4);
    int g = lin >> 5, bh = lin & 31;
    int qt = (lin < 256) ? (15 - g) : (g - 8);   // balance: CU gets qt and 15-qt
    int b = bh >> 4, hd = bh & 15, kvh = hd >> 2;
    int t0 = qt * 128;

    const u16* Qb = Qr + (((size_t)(b * NH + hd)) * T_SEQ + t0 + wid * 32) * HD;
    const u16* Kb = Kr + ((size_t)(b * NKV + kvh)) * T_SEQ * HD;
    const u16* Vb = Vt + ((size_t)(b * NKV + kvh)) * HD * T_SEQ;

    // Q as B-operand frags: col = t = l32, k = d
    short8 qf[8];
#pragma unroll
    for (int ks = 0; ks < 8; ks++)
        qf[ks] = *(const short8*)(Qb + (size_t)l32 * HD + ks * 16 + hh * 8);

    float16v oacc[4];   // O^T: rows d (dt*32 block), cols t (= l32)
#pragma unroll
    for (int dt = 0; dt < 4; dt++)
        oacc[dt] = (float16v){0,0,0,0,0,0,0,0,0,0,0,0,0,0,0,0};
    float m_run = -INFINITY, l_run = 0.f;

    int ksr = tid >> 2, kc = (tid & 3) * 32;   // K staging: row s, col base (u16)
    int vdr = tid >> 1, vc = (tid & 1) * 32;   // V staging: row d, col base (u16)
    u16* pw = plds + wid * 32 * 72;

    int nst = 2 * qt + 2;

    {   // prologue: stage tile 0
        const u16* ksrc = Kb + (size_t)ksr * HD + kc;
        const u16* vsrc = Vb + (size_t)vdr * T_SEQ + vc;
        short8 kr0[4], vr0[4];
#pragma unroll
        for (int i = 0; i < 4; i++) kr0[i] = *(const short8*)(ksrc + i * 8);
#pragma unroll
        for (int i = 0; i < 4; i++) vr0[i] = *(const short8*)(vsrc + i * 8);
#pragma unroll
        for (int i = 0; i < 4; i++) *(short8*)&klds[ksr * 136 + kc + i * 8] = kr0[i];
#pragma unroll
        for (int i = 0; i < 4; i++) *(short8*)&vlds[vdr * 72 + vc + i * 8] = vr0[i];
    }
    __syncthreads();

    for (int st = 0; st < nst; st++) {
        short8 krg[4], vrg[4];
        bool more = (st + 1 < nst);
        if (more) {   // prefetch next K/V tile into registers
            const u16* ksrc = Kb + ((size_t)(st + 1) * 64 + ksr) * HD + kc;
            const u16* vsrc = Vb + (size_t)vdr * T_SEQ + (st + 1) * 64 + vc;
#pragma unroll
            for (int i = 0; i < 4; i++) krg[i] = *(const short8*)(ksrc + i * 8);
#pragma unroll
            for (int i = 0; i < 4; i++) vrg[i] = *(const short8*)(vsrc + i * 8);
        }

        // S^T = K * Q^T : rows = s (2 tiles of 32), cols = t (32)
        float16v sfa[2];
        sfa[0] = (float16v){0,0,0,0,0,0,0,0,0,0,0,0,0,0,0,0};
        sfa[1] = (float16v){0,0,0,0,0,0,0,0,0,0,0,0,0,0,0,0};
#pragma unroll
        for (int ks = 0; ks < 8; ks++) {
            short8 kf0 = *(const short8*)&klds[l32 * 136 + ks * 16 + hh * 8];
            short8 kf1 = *(const short8*)&klds[(32 + l32) * 136 + ks * 16 + hh * 8];
            sfa[0] = __builtin_amdgcn_mfma_f32_32x32x16_bf16(kf0, qf[ks], sfa[0], 0, 0, 0);
            sfa[1] = __builtin_amdgcn_mfma_f32_32x32x16_bf16(kf1, qf[ks], sfa[1], 0, 0, 0);
        }

        int tg = t0 + wid * 32 + l32;
        if (st >= 2 * qt) {   // causal mask on diagonal tiles
#pragma unroll
            for (int stile = 0; stile < 2; stile++)
#pragma unroll
                for (int r = 0; r < 16; r++) {
                    int s = st * 64 + stile * 32 + (r & 3) + 8 * (r >> 2) + 4 * hh;
                    if (s > tg) sfa[stile][r] = -INFINITY;
                }
        }

        // online softmax over s (in-lane 32 values + one cross-half shfl)
        float mx = -INFINITY;
#pragma unroll
        for (int stile = 0; stile < 2; stile++)
#pragma unroll
            for (int r = 0; r < 16; r++) mx = fmaxf(mx, sfa[stile][r]);
        mx = fmaxf(mx, __shfl_xor(mx, 32, 64));
        float mnew = fmaxf(m_run, mx);
        float alpha = __expf(m_run - mnew);
        float psum = 0.f;
#pragma unroll
        for (int stile = 0; stile < 2; stile++)
#pragma unroll
            for (int r = 0; r < 16; r++) {
                float p = __expf(sfa[stile][r] - mnew);
                sfa[stile][r] = p;
                psum += p;
            }
        psum += __shfl_xor(psum, 32, 64);
        l_run = l_run * alpha + psum;
        m_run = mnew;

        // write P^T -> plds[t][s] packed b64 (per-wave region, no barrier needed)
#pragma unroll
        for (int stile = 0; stile < 2; stile++)
#pragma unroll
            for (int gq = 0; gq < 4; gq++) {
                ushort4v pk;
                pk.x = f32_bf16(sfa[stile][gq * 4 + 0]);
                pk.y = f32_bf16(sfa[stile][gq * 4 + 1]);
                pk.z = f32_bf16(sfa[stile][gq * 4 + 2]);
                pk.w = f32_bf16(sfa[stile][gq * 4 + 3]);
                *(ushort4v*)&pw[l32 * 72 + stile * 32 + gq * 8 + hh * 4] = pk;
            }

        // rescale O^T by alpha — per-lane scalar now
#pragma unroll
        for (int dt = 0; dt < 4; dt++)
#pragma unroll
            for (int r = 0; r < 16; r++) oacc[dt][r] *= alpha;

        // O^T += V^T * P^T : A = V^T [d][s-k], B = P^T (lane n = t, k = s)
#pragma unroll
        for (int ks2 = 0; ks2 < 4; ks2++) {
            short8 pf = *(const short8*)&pw[l32 * 72 + ks2 * 16 + hh * 8];
#pragma unroll
            for (int dt = 0; dt < 4; dt++) {
                short8 vf = *(const short8*)&vlds[(dt * 32 + l32) * 72 + ks2 * 16 + hh * 8];
                oacc[dt] = __builtin_amdgcn_mfma_f32_32x32x16_bf16(vf, pf, oacc[dt], 0, 0, 0);
            }
        }

        if (more) {
            __syncthreads();   // everyone done reading current K/V
#pragma unroll
            for (int i = 0; i < 4; i++) *(short8*)&klds[ksr * 136 + kc + i * 8] = krg[i];
#pragma unroll
            for (int i = 0; i < 4; i++) *(short8*)&vlds[vdr * 72 + vc + i * 8] = vrg[i];
            __syncthreads();
        }
    }

    // epilogue: scale (per-lane), transpose O^T -> O via per-wave LDS scratch
    const float scale = 0.022097086912079608f;   // 2048^-0.5
    float sc = scale / l_run;
    __syncthreads();                       // done with vlds/klds
    u16* ow = smem + wid * 4352;           // [t=32][d=128] stride 136
#pragma unroll
    for (int dt = 0; dt < 4; dt++)
#pragma unroll
        for (int gq = 0; gq < 4; gq++) {
            ushort4v pk;
            pk.x = f32_bf16(oacc[dt][gq * 4 + 0] * sc);
            pk.y = f32_bf16(oacc[dt][gq * 4 + 1] * sc);
            pk.z = f32_bf16(oacc[dt][gq * 4 + 2] * sc);
            pk.w = f32_bf16(oacc[dt][gq * 4 + 3] * sc);
            *(ushort4v*)&ow[l32 * 136 + dt * 32 + gq * 8 + hh * 4] = pk;
        }
    // same-wave read-back (compiler inserts lgkmcnt wait), coalesced store
    int tl = lane >> 4, dcol = (lane & 15) * 8;
#pragma unroll
    for (int ch = 0; ch < 8; ch++) {
        int t_local = tl + ch * 4;
        short8 ov = *(const short8*)&ow[t_local * 136 + dcol];
        *(short8*)&Oout[((size_t)(b * T_SEQ) + t0 + wid * 32 + t_local) * NE + hd * HD + dcol] = ov;
    }
}

// ---------------- launch ----------------
extern "C" void kernel_launch(void* const* d_in, const int* in_sizes, int n_in,
                              void* d_out, int out_size, void* d_ws, size_t ws_size,
                              hipStream_t stream) {
    const float* x  = (const float*)d_in[0];
    const float* Wq = (const float*)d_in[1];
    const float* bq = (const float*)d_in[2];
    const float* Wk = (const float*)d_in[3];
    const float* bk = (const float*)d_in[4];
    const float* Wv = (const float*)d_in[5];
    const float* bv = (const float*)d_in[6];
    const float* Wo = (const float*)d_in[7];
    const float* bo = (const float*)d_in[8];
    float* out = (float*)d_out;
    char* ws = (char*)d_ws;

    // aliasing: ao reuses xh (xh dead after KV gemm); wot reuses wqt (dead after Q gemm)
    u16* xh   = (u16*)(ws);                      // 16 MB   [also ao]
    u16* wqt  = (u16*)(ws + 16777216);           // 8 MB    [also wot]
    u16* wkt  = (u16*)(ws + 25165824);           // 2 MB  } contiguous [n=1024][k=2048]
    u16* wvt  = (u16*)(ws + 27262976);           // 2 MB  }
    u16* qr   = (u16*)(ws + 29360128);           // 16 MB
    u16* kr   = (u16*)(ws + 46137344);           // 4 MB
    u16* vt   = (u16*)(ws + 50331648);           // 4 MB
    float* ctab = (float*)(ws + 54525952);       // 0.5 MB
    float* stab = (float*)(ws + 55050240);       // 0.5 MB
    u16* ao  = xh;
    u16* wot = wqt;

    conv_f16<<<8192, 256, 0, stream>>>(x, xh);
    transpose_convert<true><<<dim3(64, 64), dim3(32, 8), 0, stream>>>(Wq, wqt, 2048, 2048);
    transpose_convert<true><<<dim3(16, 64), dim3(32, 8), 0, stream>>>(Wk, wkt, 2048, 512);
    transpose_convert<true><<<dim3(16, 64), dim3(32, 8), 0, stream>>>(Wv, wvt, 2048, 512);
    rope_tab<<<512, 256, 0, stream>>>(ctab, stab);

    gemm_bt<0, true><<<dim3(32, 16), 256, 0, stream>>>(xh, wqt, bq, nullptr, qr, nullptr, nullptr, ctab, stab);
    gemm_bt<4, true><<<dim3(32, 8), 256, 0, stream>>>(xh, wkt, bk, bv, kr, vt, nullptr, ctab, stab);

    // Wo transpose after Q gemm (wqt dead), before final gemm
    transpose_convert<false><<<dim3(64, 64), dim3(32, 8), 0, stream>>>(Wo, wot, 2048, 2048);

    attn_kernel<<<dim3(16, 32), 256, 0, stream>>>(qr, kr, vt, ao);

    gemm_bt<3, false><<<dim3(32, 16), 256, 0, stream>>>(ao, wot, bo, nullptr, nullptr, nullptr, out, ctab, stab);
}

// Round 6
// 403.766 us; speedup vs baseline: 1.2552x; 1.2380x over previous
//
#include <hip/hip_runtime.h>
#include <stdint.h>
#include <math.h>

typedef unsigned short u16;
typedef __attribute__((ext_vector_type(8))) short short8;
typedef __attribute__((ext_vector_type(8))) _Float16 half8;
typedef __attribute__((ext_vector_type(4))) float float4v;
typedef __attribute__((ext_vector_type(16))) float float16v;
typedef __attribute__((ext_vector_type(4))) u16 ushort4v;

#define T_SEQ 2048
#define NB 2
#define NE 2048
#define NH 16
#define NKV 4
#define HD 128
#define KDIM 2048

union Frag { short8 s; half8 h; };

__device__ inline u16 f32_bf16(float f) {
    union { float f; uint32_t u; } v; v.f = f;
    uint32_t u = v.u;
    return (u16)((u + 0x7fffu + ((u >> 16) & 1u)) >> 16);
}
__device__ inline u16 f32_f16(float f) {
    union { _Float16 h; u16 u; } v; v.h = (_Float16)f;
    return v.u;
}

// ---------------- conversion kernels ----------------
__global__ void conv_f16(const float* __restrict__ in, u16* __restrict__ out) {
    int i = blockIdx.x * blockDim.x + threadIdx.x;
    float4 v = ((const float4*)in)[i];
    ushort4v o;
    o.x = f32_f16(v.x); o.y = f32_f16(v.y); o.z = f32_f16(v.z); o.w = f32_f16(v.w);
    *(ushort4v*)(out + (size_t)i * 4) = o;
}

template<bool TO_F16>
__global__ void transpose_convert(const float* __restrict__ in, u16* __restrict__ out,
                                  int K, int N) {
    __shared__ float tile[32][33];
    int n0 = blockIdx.x * 32, k0 = blockIdx.y * 32;
    int tx = threadIdx.x, ty = threadIdx.y;   // 32 x 8
    for (int i = 0; i < 32; i += 8)
        tile[ty + i][tx] = in[(size_t)(k0 + ty + i) * N + n0 + tx];
    __syncthreads();
    for (int i = 0; i < 32; i += 8) {
        float v = tile[tx][ty + i];
        out[(size_t)(n0 + ty + i) * K + k0 + tx] = TO_F16 ? f32_f16(v) : f32_bf16(v);
    }
}

__global__ void rope_tab(float* __restrict__ ctab, float* __restrict__ stab) {
    int i = blockIdx.x * blockDim.x + threadIdx.x;   // < 2048*64
    int t = i >> 6, j = i & 63;
    float freqf = (float)pow(10000.0, -(double)j / 1024.0);
    float angf = (float)t * freqf;          // fp32 rounding like np.outer
    double a = (double)angf;
    ctab[i] = (float)cos(a);
    stab[i] = (float)sin(a);
}

// ---------------- GEMM: C[M,N] = A[M,K] @ Bt[N,K]^T, fused epilogues ----------------
// EXACT R2 structure (known-good): in-loop reg staging, no prefetch.
// MODE: 0 = Q (rope->bf16, [B,H,T,D]), 1 = K (rope->bf16, [B,KVH,T,D]),
//       2 = V (bf16, [B,KVH,D,T]),     3 = OUT (fp32 + bias -> d_out)
template<int MODE, bool F16IN>
__global__ __launch_bounds__(256)
void gemm_bt(const u16* __restrict__ A, const u16* __restrict__ Bt,
             const float* __restrict__ bias,
             u16* __restrict__ outU, float* __restrict__ outF,
             const float* __restrict__ ctab, const float* __restrict__ stab) {
    __shared__ u16 Alds[128 * 40];
    __shared__ u16 Blds[128 * 40];
    int tid = threadIdx.x;
    int wid = tid >> 6, lane = tid & 63;
    int quad = lane >> 4, l16 = lane & 15;
    int wr = wid >> 1, wc = wid & 1;
    int m0 = blockIdx.x * 128, n0 = blockIdx.y * 128;

    float4v acc[4][4];
    for (int i = 0; i < 4; i++) for (int j = 0; j < 4; j++) acc[i][j] = (float4v){0,0,0,0};

    int sr = tid >> 2;      // 0..63
    int sq = tid & 3;       // k-group of 8
    const u16* Ag = A + (size_t)(m0 + sr) * KDIM + sq * 8;
    const u16* Bg = Bt + (size_t)(n0 + sr) * KDIM + sq * 8;

    for (int k0 = 0; k0 < KDIM; k0 += 32) {
        short8 av0 = *(const short8*)(Ag + k0);
        short8 av1 = *(const short8*)(Ag + (size_t)64 * KDIM + k0);
        short8 bv0 = *(const short8*)(Bg + k0);
        short8 bv1 = *(const short8*)(Bg + (size_t)64 * KDIM + k0);
        __syncthreads();
        *(short8*)&Alds[sr * 40 + sq * 8] = av0;
        *(short8*)&Alds[(sr + 64) * 40 + sq * 8] = av1;
        *(short8*)&Blds[sr * 40 + sq * 8] = bv0;
        *(short8*)&Blds[(sr + 64) * 40 + sq * 8] = bv1;
        __syncthreads();

        Frag af[4], bf[4];
        for (int i = 0; i < 4; i++)
            af[i].s = *(const short8*)&Alds[(wr * 64 + i * 16 + l16) * 40 + quad * 8];
        for (int j = 0; j < 4; j++)
            bf[j].s = *(const short8*)&Blds[(wc * 64 + j * 16 + l16) * 40 + quad * 8];
        for (int i = 0; i < 4; i++)
            for (int j = 0; j < 4; j++) {
                if (F16IN)
                    acc[i][j] = __builtin_amdgcn_mfma_f32_16x16x32_f16(af[i].h, bf[j].h, acc[i][j], 0, 0, 0);
                else
                    acc[i][j] = __builtin_amdgcn_mfma_f32_16x16x32_bf16(af[i].s, bf[j].s, acc[i][j], 0, 0, 0);
            }
    }

    // epilogue
    for (int i = 0; i < 4; i++) {
        int mbase = m0 + wr * 64 + i * 16 + quad * 4;
        for (int j = 0; j < 4; j++) {
            int col = n0 + wc * 64 + j * 16 + l16;
            float bcol = bias[col];
            for (int r = 0; r < 4; r++) {
                int m = mbase + r;
                float val = acc[i][j][r] + bcol;
                if (MODE == 3) {
                    outF[(size_t)m * NE + col] = val;
                } else if (MODE == 2) {
                    int b = m >> 11, t = m & 2047;
                    int h = col >> 7, d = col & 127;
                    outU[(((size_t)(b * NKV + h)) * HD + d) * T_SEQ + t] = f32_bf16(val);
                } else {
                    int b = m >> 11, t = m & 2047;
                    int h = col >> 7, d = col & 127;
                    int jj = d >> 1;
                    float c = ctab[t * 64 + jj];
                    float s = stab[t * 64 + jj];
                    float partner = __shfl_xor(val, 1, 64);
                    float o = (d & 1) ? (partner * s + val * c) : (val * c - partner * s);
                    u16 ob = f32_bf16(o);
                    if (MODE == 0)
                        outU[(((size_t)(b * NH + h)) * T_SEQ + t) * HD + d] = ob;
                    else
                        outU[(((size_t)(b * NKV + h)) * T_SEQ + t) * HD + d] = ob;
                }
            }
        }
    }
}

// ---------------- flash attention v3h (hardened barriers) ----------------
// Transposed-S and transposed-O; alpha/l are per-lane scalars. All LDS
// producer->consumer edges are barrier-protected (no reliance on same-wave
// DS ordering or compiler alias analysis) — fixes the warm-replay race.
__global__ __launch_bounds__(256, 2)
void attn_kernel(const u16* __restrict__ Qr, const u16* __restrict__ Kr,
                 const u16* __restrict__ Vt, u16* __restrict__ Oout) {
    __shared__ u16 smem[27136];            // 54272 B total
    u16* klds = smem;                      // K tile [s=64][d=128] stride 136
    u16* vlds = smem + 8704;               // V^T tile [d=128][s=64] stride 72
    u16* plds = smem + 17920;              // per-wave P [t=32][s=64] stride 72
    int tid = threadIdx.x;
    int wid = tid >> 6, lane = tid & 63;
    int l32 = lane & 31, hh = lane >> 5;

    int lin = blockIdx.x + (blockIdx.y << 4);
    int g = lin >> 5, bh = lin & 31;
    int qt = (lin < 256) ? (15 - g) : (g - 8);   // balance: CU gets qt and 15-qt
    int b = bh >> 4, hd = bh & 15, kvh = hd >> 2;
    int t0 = qt * 128;

    const u16* Qb = Qr + (((size_t)(b * NH + hd)) * T_SEQ + t0 + wid * 32) * HD;
    const u16* Kb = Kr + ((size_t)(b * NKV + kvh)) * T_SEQ * HD;
    const u16* Vb = Vt + ((size_t)(b * NKV + kvh)) * HD * T_SEQ;

    // Q as B-operand frags: col = t = l32, k = d
    short8 qf[8];
#pragma unroll
    for (int ks = 0; ks < 8; ks++)
        qf[ks] = *(const short8*)(Qb + (size_t)l32 * HD + ks * 16 + hh * 8);

    float16v oacc[4];   // O^T: rows d (dt*32 block), cols t (= l32)
#pragma unroll
    for (int dt = 0; dt < 4; dt++)
        oacc[dt] = (float16v){0,0,0,0,0,0,0,0,0,0,0,0,0,0,0,0};
    float m_run = -INFINITY, l_run = 0.f;

    int ksr = tid >> 2, kc = (tid & 3) * 32;   // K staging: row s, col base (u16)
    int vdr = tid >> 1, vc = (tid & 1) * 32;   // V staging: row d, col base (u16)
    u16* pw = plds + wid * 32 * 72;

    int nst = 2 * qt + 2;

    {   // prologue: stage tile 0
        const u16* ksrc = Kb + (size_t)ksr * HD + kc;
        const u16* vsrc = Vb + (size_t)vdr * T_SEQ + vc;
        short8 kr0[4], vr0[4];
#pragma unroll
        for (int i = 0; i < 4; i++) kr0[i] = *(const short8*)(ksrc + i * 8);
#pragma unroll
        for (int i = 0; i < 4; i++) vr0[i] = *(const short8*)(vsrc + i * 8);
#pragma unroll
        for (int i = 0; i < 4; i++) *(short8*)&klds[ksr * 136 + kc + i * 8] = kr0[i];
#pragma unroll
        for (int i = 0; i < 4; i++) *(short8*)&vlds[vdr * 72 + vc + i * 8] = vr0[i];
    }
    __syncthreads();

    for (int st = 0; st < nst; st++) {
        short8 krg[4], vrg[4];
        bool more = (st + 1 < nst);
        if (more) {   // prefetch next K/V tile into registers
            const u16* ksrc = Kb + ((size_t)(st + 1) * 64 + ksr) * HD + kc;
            const u16* vsrc = Vb + (size_t)vdr * T_SEQ + (st + 1) * 64 + vc;
#pragma unroll
            for (int i = 0; i < 4; i++) krg[i] = *(const short8*)(ksrc + i * 8);
#pragma unroll
            for (int i = 0; i < 4; i++) vrg[i] = *(const short8*)(vsrc + i * 8);
        }

        // S^T = K * Q^T : rows = s (2 tiles of 32), cols = t (32)
        float16v sfa[2];
        sfa[0] = (float16v){0,0,0,0,0,0,0,0,0,0,0,0,0,0,0,0};
        sfa[1] = (float16v){0,0,0,0,0,0,0,0,0,0,0,0,0,0,0,0};
#pragma unroll
        for (int ks = 0; ks < 8; ks++) {
            short8 kf0 = *(const short8*)&klds[l32 * 136 + ks * 16 + hh * 8];
            short8 kf1 = *(const short8*)&klds[(32 + l32) * 136 + ks * 16 + hh * 8];
            sfa[0] = __builtin_amdgcn_mfma_f32_32x32x16_bf16(kf0, qf[ks], sfa[0], 0, 0, 0);
            sfa[1] = __builtin_amdgcn_mfma_f32_32x32x16_bf16(kf1, qf[ks], sfa[1], 0, 0, 0);
        }

        int tg = t0 + wid * 32 + l32;
        if (st >= 2 * qt) {   // causal mask on diagonal tiles
#pragma unroll
            for (int stile = 0; stile < 2; stile++)
#pragma unroll
                for (int r = 0; r < 16; r++) {
                    int s = st * 64 + stile * 32 + (r & 3) + 8 * (r >> 2) + 4 * hh;
                    if (s > tg) sfa[stile][r] = -INFINITY;
                }
        }

        // online softmax over s (in-lane 32 values + one cross-half shfl)
        float mx = -INFINITY;
#pragma unroll
        for (int stile = 0; stile < 2; stile++)
#pragma unroll
            for (int r = 0; r < 16; r++) mx = fmaxf(mx, sfa[stile][r]);
        mx = fmaxf(mx, __shfl_xor(mx, 32, 64));
        float mnew = fmaxf(m_run, mx);
        float alpha = __expf(m_run - mnew);
        float psum = 0.f;
#pragma unroll
        for (int stile = 0; stile < 2; stile++)
#pragma unroll
            for (int r = 0; r < 16; r++) {
                float p = __expf(sfa[stile][r] - mnew);
                sfa[stile][r] = p;
                psum += p;
            }
        psum += __shfl_xor(psum, 32, 64);
        l_run = l_run * alpha + psum;
        m_run = mnew;

        // write P^T -> plds[t][s] packed b64 (per-wave region)
#pragma unroll
        for (int stile = 0; stile < 2; stile++)
#pragma unroll
            for (int gq = 0; gq < 4; gq++) {
                ushort4v pk;
                pk.x = f32_bf16(sfa[stile][gq * 4 + 0]);
                pk.y = f32_bf16(sfa[stile][gq * 4 + 1]);
                pk.z = f32_bf16(sfa[stile][gq * 4 + 2]);
                pk.w = f32_bf16(sfa[stile][gq * 4 + 3]);
                *(ushort4v*)&pw[l32 * 72 + stile * 32 + gq * 8 + hh * 4] = pk;
            }

        __syncthreads();   // P writes fully visible before PV reads (hard LDS fence)

        // rescale O^T by alpha — per-lane scalar
#pragma unroll
        for (int dt = 0; dt < 4; dt++)
#pragma unroll
            for (int r = 0; r < 16; r++) oacc[dt][r] *= alpha;

        // O^T += V^T * P^T : A = V^T [d][s-k], B = P^T (lane n = t, k = s)
#pragma unroll
        for (int ks2 = 0; ks2 < 4; ks2++) {
            short8 pf = *(const short8*)&pw[l32 * 72 + ks2 * 16 + hh * 8];
#pragma unroll
            for (int dt = 0; dt < 4; dt++) {
                short8 vf = *(const short8*)&vlds[(dt * 32 + l32) * 72 + ks2 * 16 + hh * 8];
                oacc[dt] = __builtin_amdgcn_mfma_f32_32x32x16_bf16(vf, pf, oacc[dt], 0, 0, 0);
            }
        }

        __syncthreads();   // all K/V (and P) reads done before overwrite
        if (more) {
#pragma unroll
            for (int i = 0; i < 4; i++) *(short8*)&klds[ksr * 136 + kc + i * 8] = krg[i];
#pragma unroll
            for (int i = 0; i < 4; i++) *(short8*)&vlds[vdr * 72 + vc + i * 8] = vrg[i];
        }
        __syncthreads();   // staging visible before next iteration's reads
    }

    // epilogue: scale (per-lane), transpose O^T -> O via LDS scratch
    const float scale = 0.022097086912079608f;   // 2048^-0.5
    float sc = scale / l_run;
    u16* ow = smem + wid * 4352;           // [t=32][d=128] stride 136
#pragma unroll
    for (int dt = 0; dt < 4; dt++)
#pragma unroll
        for (int gq = 0; gq < 4; gq++) {
            ushort4v pk;
            pk.x = f32_bf16(oacc[dt][gq * 4 + 0] * sc);
            pk.y = f32_bf16(oacc[dt][gq * 4 + 1] * sc);
            pk.z = f32_bf16(oacc[dt][gq * 4 + 2] * sc);
            pk.w = f32_bf16(oacc[dt][gq * 4 + 3] * sc);
            *(ushort4v*)&ow[l32 * 136 + dt * 32 + gq * 8 + hh * 4] = pk;
        }
    __syncthreads();   // transpose writes visible before read-back
    int tl = lane >> 4, dcol = (lane & 15) * 8;
#pragma unroll
    for (int ch = 0; ch < 8; ch++) {
        int t_local = tl + ch * 4;
        short8 ov = *(const short8*)&ow[t_local * 136 + dcol];
        *(short8*)&Oout[((size_t)(b * T_SEQ) + t0 + wid * 32 + t_local) * NE + hd * HD + dcol] = ov;
    }
}

// ---------------- launch ----------------
extern "C" void kernel_launch(void* const* d_in, const int* in_sizes, int n_in,
                              void* d_out, int out_size, void* d_ws, size_t ws_size,
                              hipStream_t stream) {
    const float* x  = (const float*)d_in[0];
    const float* Wq = (const float*)d_in[1];
    const float* bq = (const float*)d_in[2];
    const float* Wk = (const float*)d_in[3];
    const float* bk = (const float*)d_in[4];
    const float* Wv = (const float*)d_in[5];
    const float* bv = (const float*)d_in[6];
    const float* Wo = (const float*)d_in[7];
    const float* bo = (const float*)d_in[8];
    float* out = (float*)d_out;
    char* ws = (char*)d_ws;

    // aliasing: ao reuses xh (xh dead after V gemm); wot reuses wqt (dead after Q gemm)
    u16* xh   = (u16*)(ws);                      // 16 MB   [also ao]
    u16* wqt  = (u16*)(ws + 16777216);           // 8 MB    [also wot]
    u16* wkt  = (u16*)(ws + 25165824);           // 2 MB
    u16* wvt  = (u16*)(ws + 27262976);           // 2 MB
    u16* qr   = (u16*)(ws + 29360128);           // 16 MB
    u16* kr   = (u16*)(ws + 46137344);           // 4 MB
    u16* vt   = (u16*)(ws + 50331648);           // 4 MB
    float* ctab = (float*)(ws + 54525952);       // 0.5 MB
    float* stab = (float*)(ws + 55050240);       // 0.5 MB
    u16* ao  = xh;
    u16* wot = wqt;

    conv_f16<<<8192, 256, 0, stream>>>(x, xh);
    transpose_convert<true><<<dim3(64, 64), dim3(32, 8), 0, stream>>>(Wq, wqt, 2048, 2048);
    transpose_convert<true><<<dim3(16, 64), dim3(32, 8), 0, stream>>>(Wk, wkt, 2048, 512);
    transpose_convert<true><<<dim3(16, 64), dim3(32, 8), 0, stream>>>(Wv, wvt, 2048, 512);
    rope_tab<<<512, 256, 0, stream>>>(ctab, stab);

    gemm_bt<0, true><<<dim3(32, 16), 256, 0, stream>>>(xh, wqt, bq, qr, nullptr, ctab, stab);
    gemm_bt<1, true><<<dim3(32, 4), 256, 0, stream>>>(xh, wkt, bk, kr, nullptr, ctab, stab);
    gemm_bt<2, true><<<dim3(32, 4), 256, 0, stream>>>(xh, wvt, bv, vt, nullptr, ctab, stab);

    // Wo transpose after Q gemm (wqt dead), before final gemm
    transpose_convert<false><<<dim3(64, 64), dim3(32, 8), 0, stream>>>(Wo, wot, 2048, 2048);

    attn_kernel<<<dim3(16, 32), 256, 0, stream>>>(qr, kr, vt, ao);

    gemm_bt<3, false><<<dim3(32, 16), 256, 0, stream>>>(ao, wot, bo, nullptr, out, ctab, stab);
}